// Round 7
// baseline (367.426 us; speedup 1.0000x reference)
//
#include <hip/hip_runtime.h>
#include <hip/hip_bf16.h>

#define NBR   8
#define DV    256    // VOCAB
#define FF    1024   // FFN
#define RT    192    // rows per block tile
#define NCHUNK 16    // FFN chunks of 64
#define NTILES 86    // ceil(16384/192)
#define NROWS 16384

// LDS (bytes): B1 dbuf 2x32K @0 | B2 dbuf 2x32K @64K | Hs [192][64] 24K @128K | bias 4K
#define L_B1   0
#define L_B2   65536
#define L_HS   131072
#define L_BIAS 155648
#define LDS_BYTES 159744

using bf16x8 = __attribute__((ext_vector_type(8))) short;
using f32x4  = __attribute__((ext_vector_type(4))) float;

__device__ __forceinline__ unsigned short f2bf(float f) {
    unsigned int u = __builtin_bit_cast(unsigned int, f);
    unsigned int r = (u + 0x7fffu + ((u >> 16) & 1u)) >> 16;
    return (unsigned short)r;
}
// gelu(x) ~= x * sigmoid(1.595769122x + 0.0713548163x^3), exp2 domain
__device__ __forceinline__ float gelu_fast(float x) {
    float x2 = x * x;
    float z  = x * fmaf(x2, -0.1029434959f, -2.3022078770f);
    float e  = __builtin_amdgcn_exp2f(z);
    return x * __builtin_amdgcn_rcpf(1.0f + e);
}

#define GLL(gsrc, ldst) __builtin_amdgcn_global_load_lds((const unsigned int*)(gsrc), (unsigned int*)(ldst), 16, 0, 0)
#define MFMA16 __builtin_amdgcn_mfma_f32_16x16x32_bf16
#define BAR()    do { asm volatile("" ::: "memory"); __builtin_amdgcn_s_barrier(); asm volatile("" ::: "memory"); } while (0)
#define VMCNT0() asm volatile("s_waitcnt vmcnt(0)" ::: "memory")
#define LGKM0()  asm volatile("s_waitcnt lgkmcnt(0)" ::: "memory")

// ---------------- prep: fp32 weights -> bf16 swizzled LDS chunk images ----------------
// w1img per (n,c): 32KB Bt1 [64 nn][256 kk]: val = U1[n][kk][c*64+nn], byte ^= (nn&7)<<4
// w2img per (n,c): 32KB Bt2 [256 nn][64 kk]: val = U2[n][c*64+kk][nn], byte ^= (nn&7)<<4
__global__ void prep_weights(const float* __restrict__ U1, const float* __restrict__ U2,
                             unsigned short* __restrict__ w1img, unsigned short* __restrict__ w2img)
{
    const int b = blockIdx.x;          // 0..127 : n*16 + c
    const int n = b >> 4, cch = b & 15;
    const int tid = threadIdx.x;       // 0..255
    char* img1 = (char*)(w1img) + ((size_t)b << 15);
    char* img2 = (char*)(w2img) + ((size_t)b << 15);
    const float* U1n = U1 + (size_t)n * DV * FF;
    const float* U2n = U2 + (size_t)n * FF * DV;
    #pragma unroll 4
    for (int e = 0; e < 64; ++e) {
        int kk = e * 4 + (tid >> 6);
        int nn = tid & 63;
        float v = U1n[(size_t)kk * FF + cch * 64 + nn];
        unsigned off = ((unsigned)(nn * 256 + kk) * 2u) ^ (unsigned)((nn & 7) << 4);
        *(unsigned short*)(img1 + off) = f2bf(v);
    }
    #pragma unroll 4
    for (int e = 0; e < 64; ++e) {
        int nn = tid;  // 0..255
        float v = U2n[(size_t)(cch * 64 + e) * DV + nn];
        unsigned off = ((unsigned)(nn * 64 + e) * 2u) ^ (unsigned)((nn & 7) << 4);
        *(unsigned short*)(img2 + off) = f2bf(v);
    }
}

// ---------------- main: 12 waves, 3 waves/SIMD, 2 barriers/chunk, role-split staging ----------------
__global__ __launch_bounds__(768, 3)
void belayer_main(const float* __restrict__ x,
                  const unsigned short* __restrict__ w1img,
                  const unsigned short* __restrict__ w2img,
                  const float* __restrict__ b1g, const float* __restrict__ b2g,
                  const float* __restrict__ lnw, const float* __restrict__ lnb,
                  float* __restrict__ out)
{
    __shared__ __align__(16) char LDS[LDS_BYTES];
    const int tid  = threadIdx.x;
    const int lane = tid & 63;
    const int wave = tid >> 6;          // 0..11
    const int q = lane >> 4, c = lane & 15;
    const int n    = blockIdx.x & 7;    // branch == XCD affinity
    const int tile = blockIdx.x >> 3;   // 0..85
    const int row0 = tile * RT;
    const int rowg   = wave >> 1, colsel = wave & 1;   // G1: 32 rows x 32 ffn per wave (6x2)
    const int rowg2  = wave >> 2, colg2  = wave & 3;   // G2: 64 rows x 64 cols per wave (3x4)
    const unsigned swz = (unsigned)((c & 7) << 4);
    const bool isB1stager = (wave < 8);

    const char* g1base = (const char*)w1img + ((size_t)(n * NCHUNK) << 15) + (wave << 12) + lane * 16;
    const char* g2base = (const char*)w2img + ((size_t)(n * NCHUNK) << 15) + ((wave - 8) << 13) + lane * 16;

    // ---- prologue staging: w0-7 stage B1[0] (4 GLL), w8-11 stage B2[0] (8 GLL) ----
    if (isB1stager) {
        #pragma unroll
        for (int i = 0; i < 4; ++i) GLL(g1base + (i << 10), LDS + L_B1 + (wave << 12) + (i << 10));
    } else {
        #pragma unroll
        for (int i = 0; i < 8; ++i) GLL(g2base + (i << 10), LDS + L_B2 + ((wave - 8) << 13) + (i << 10));
    }

    // ---- A-frags resident (64 VGPR): rows rowg*32 + rf*16 + c (clamped) ----
    bf16x8 A[2][8];
    #pragma unroll
    for (int rf = 0; rf < 2; ++rf) {
        int grow = row0 + rowg * 32 + rf * 16 + c;
        if (grow > NROWS - 1) grow = NROWS - 1;
        const float* src = x + ((size_t)grow * NBR + n) * DV + q * 8;
        #pragma unroll
        for (int ks = 0; ks < 8; ++ks) {
            f32x4 v0 = *(const f32x4*)(src + ks * 32);
            f32x4 v1 = *(const f32x4*)(src + ks * 32 + 4);
            bf16x8 h;
            h[0] = (short)f2bf(v0[0]); h[1] = (short)f2bf(v0[1]);
            h[2] = (short)f2bf(v0[2]); h[3] = (short)f2bf(v0[3]);
            h[4] = (short)f2bf(v1[0]); h[5] = (short)f2bf(v1[1]);
            h[6] = (short)f2bf(v1[2]); h[7] = (short)f2bf(v1[3]);
            A[rf][ks] = h;
        }
    }
    // ---- bias b1[n] -> LDS ----
    {
        float* bl = (float*)(LDS + L_BIAS);
        bl[tid] = b1g[n * FF + tid];
        if (tid < 256) bl[768 + tid] = b1g[n * FF + 768 + tid];
    }
    LGKM0();   // drain bias ds_writes; first loop barrier publishes them

    // ---- swizzled LDS addresses (dual even/odd-k bases; swz touches bits 4-6 only) ----
    const unsigned nn1  = (unsigned)(colsel * 32 + c);
    const unsigned aB1e = (nn1 * 512 + q * 16) ^ swz;         // +cf*8192, +(ks>>1)*128 post-xor
    const unsigned aB1o = (nn1 * 512 + q * 16 + 64) ^ swz;
    const unsigned rr2  = (unsigned)(rowg2 * 64 + c);
    const unsigned aHe  = (rr2 * 128 + q * 16) ^ swz;          // +rf*2048 post-xor
    const unsigned aHo  = (rr2 * 128 + q * 16 + 64) ^ swz;
    const unsigned nn2  = (unsigned)(colg2 * 64 + c);
    const unsigned aB2e = (nn2 * 128 + q * 16) ^ swz;          // +cf*2048 post-xor
    const unsigned aB2o = (nn2 * 128 + q * 16 + 64) ^ swz;
    unsigned aW[4][2];
    #pragma unroll
    for (int r = 0; r < 4; ++r)
        #pragma unroll
        for (int cf = 0; cf < 2; ++cf)
            aW[r][cf] = (unsigned)(((rowg * 32 + q * 4 + r) * 128 + (colsel * 32 + cf * 16 + c) * 2)
                                   ^ (((q * 4 + r) & 7) << 4));   // +rf*2048 post-xor

    f32x4 acc2[4][4];
    #pragma unroll
    for (int i = 0; i < 4; ++i)
        #pragma unroll
        for (int j = 0; j < 4; ++j) acc2[i][j] = (f32x4){0.f, 0.f, 0.f, 0.f};

    const float* bl = (const float*)(LDS + L_BIAS);

    for (int t = 0; t < NCHUNK; ++t) {
        const unsigned hb1 = L_B1 + ((unsigned)(t & 1) << 15);
        const unsigned hb2 = L_B2 + ((unsigned)(t & 1) << 15);

        // ---- publish B1[t] (stagers drain own vmcnt) ----
        if (isB1stager) VMCNT0();
        BAR();
        // issue B1[t+1] (overlaps G1 compute; lands in other half)
        if (isB1stager && (t + 1 < NCHUNK)) {
            const char* g = g1base + ((size_t)(t + 1) << 15);
            char* l = LDS + L_B1 + (((t + 1) & 1) << 15) + (wave << 12);
            #pragma unroll
            for (int i = 0; i < 4; ++i) GLL(g + (i << 10), l + (i << 10));
        }
        // ---- G1: 32 MFMA, A resident, B1 from LDS; gelu -> Hs ----
        #pragma unroll
        for (int cf = 0; cf < 2; ++cf) {
            f32x4 a0 = (f32x4){0.f, 0.f, 0.f, 0.f};
            f32x4 a1 = (f32x4){0.f, 0.f, 0.f, 0.f};
            #pragma unroll
            for (int ks = 0; ks < 8; ++ks) {
                const unsigned addr = ((ks & 1) ? aB1o : aB1e) + hb1 + (unsigned)cf * 8192 + (unsigned)(ks >> 1) * 128;
                bf16x8 b = *(const bf16x8*)(LDS + addr);
                a0 = MFMA16(A[0][ks], b, a0, 0, 0, 0);
                a1 = MFMA16(A[1][ks], b, a1, 0, 0, 0);
            }
            float bv = bl[t * 64 + colsel * 32 + cf * 16 + c];
            #pragma unroll
            for (int rf = 0; rf < 2; ++rf) {
                f32x4 av = rf ? a1 : a0;
                #pragma unroll
                for (int r = 0; r < 4; ++r) {
                    float g = gelu_fast(av[r] + bv);
                    *(unsigned short*)(LDS + L_HS + aW[r][cf] + (unsigned)rf * 2048) = f2bf(g);
                }
            }
        }
        LGKM0();                      // drain Hs ds_writes before publish
        if (!isB1stager) VMCNT0();    // drain own B2[t] arrivals
        BAR();                        // Hs[t] + B2[t] visible
        // issue B2[t+1] (overlaps G2 compute)
        if (!isB1stager && (t + 1 < NCHUNK)) {
            const char* g = g2base + ((size_t)(t + 1) << 15);
            char* l = LDS + L_B2 + (((t + 1) & 1) << 15) + ((wave - 8) << 13);
            #pragma unroll
            for (int i = 0; i < 8; ++i) GLL(g + (i << 10), l + (i << 10));
        }
        // ---- G2: 32 MFMA, A from Hs, B from B2; accumulate ----
        #pragma unroll
        for (int ks = 0; ks < 2; ++ks) {
            bf16x8 bfr[4];
            #pragma unroll
            for (int cf = 0; cf < 4; ++cf)
                bfr[cf] = *(const bf16x8*)(LDS + hb2 + (ks ? aB2o : aB2e) + (unsigned)cf * 2048);
            #pragma unroll
            for (int rf = 0; rf < 4; ++rf) {
                bf16x8 a = *(const bf16x8*)(LDS + L_HS + (ks ? aHo : aHe) + (unsigned)rf * 2048);
                __builtin_amdgcn_s_setprio(1);
                #pragma unroll
                for (int cf = 0; cf < 4; ++cf)
                    acc2[rf][cf] = MFMA16(a, bfr[cf], acc2[rf][cf], 0, 0, 0);
                __builtin_amdgcn_s_setprio(0);
            }
        }
    }

    __syncthreads();   // all G2 reads done; LDS free for Lred

    // ---- epilogue: +b2, cross-wave LN(256), gelu, +skip, predicated store ----
    float b2v[4];
    #pragma unroll
    for (int cf = 0; cf < 4; ++cf) b2v[cf] = b2g[n * DV + colg2 * 64 + cf * 16 + c];

    float sA[4][4], sQ[4][4];
    #pragma unroll
    for (int rf = 0; rf < 4; ++rf)
        #pragma unroll
        for (int r = 0; r < 4; ++r) { sA[rf][r] = 0.f; sQ[rf][r] = 0.f; }
    #pragma unroll
    for (int rf = 0; rf < 4; ++rf)
        #pragma unroll
        for (int cf = 0; cf < 4; ++cf)
            #pragma unroll
            for (int r = 0; r < 4; ++r) {
                float v = acc2[rf][cf][r] + b2v[cf];
                acc2[rf][cf][r] = v;
                sA[rf][r] += v;
                sQ[rf][r] += v * v;
            }
    #pragma unroll
    for (int m = 1; m < 16; m <<= 1)
        #pragma unroll
        for (int rf = 0; rf < 4; ++rf)
            #pragma unroll
            for (int r = 0; r < 4; ++r) {
                sA[rf][r] += __shfl_xor(sA[rf][r], m, 64);
                sQ[rf][r] += __shfl_xor(sQ[rf][r], m, 64);
            }
    float* Lred = (float*)(LDS + L_HS);   // [colg2*192+row] s, +768 sq : 6KB
    if (c == 0) {
        #pragma unroll
        for (int rf = 0; rf < 4; ++rf)
            #pragma unroll
            for (int r = 0; r < 4; ++r) {
                int row = rowg2 * 64 + rf * 16 + q * 4 + r;
                Lred[colg2 * 192 + row]       = sA[rf][r];
                Lred[768 + colg2 * 192 + row] = sQ[rf][r];
            }
    }
    __syncthreads();
    float mu[4][4], rs[4][4];
    #pragma unroll
    for (int rf = 0; rf < 4; ++rf)
        #pragma unroll
        for (int r = 0; r < 4; ++r) {
            int row = rowg2 * 64 + rf * 16 + q * 4 + r;
            float ssum = Lred[row] + Lred[192 + row] + Lred[384 + row] + Lred[576 + row];
            float qsum = Lred[768 + row] + Lred[960 + row] + Lred[1152 + row] + Lred[1344 + row];
            float m_ = ssum * (1.0f / 256.0f);
            float var = qsum * (1.0f / 256.0f) - m_ * m_;
            mu[rf][r] = m_;
            rs[rf][r] = rsqrtf(var + 1e-5f);
        }
    #pragma unroll
    for (int cf = 0; cf < 4; ++cf) {
        int col = colg2 * 64 + cf * 16 + c;
        float lw = lnw[col];
        float lb = lnb[col];
        #pragma unroll
        for (int rf = 0; rf < 4; ++rf)
            #pragma unroll
            for (int r = 0; r < 4; ++r) {
                int row = rowg2 * 64 + rf * 16 + q * 4 + r;
                int grow = row0 + row;
                if (grow < NROWS) {
                    float v = (acc2[rf][cf][r] - mu[rf][r]) * rs[rf][r] * lw + lb;
                    float g = gelu_fast(v);
                    size_t oi = ((size_t)grow * NBR + n) * DV + col;
                    out[oi] = x[oi] + g;
                }
            }
    }
}

extern "C" void kernel_launch(void* const* d_in, const int* in_sizes, int n_in,
                              void* d_out, int out_size, void* d_ws, size_t ws_size,
                              hipStream_t stream) {
    const float* x   = (const float*)d_in[0];
    const float* U1  = (const float*)d_in[1];
    const float* b1  = (const float*)d_in[2];
    const float* U2  = (const float*)d_in[3];
    const float* b2  = (const float*)d_in[4];
    const float* lnw = (const float*)d_in[5];
    const float* lnb = (const float*)d_in[6];
    float* out = (float*)d_out;

    unsigned short* w1img = (unsigned short*)d_ws;               // 4 MB
    unsigned short* w2img = w1img + (size_t)4 * 1024 * 1024 / 2; // 4 MB

    prep_weights<<<dim3(128), dim3(256), 0, stream>>>(U1, U2, w1img, w2img);
    belayer_main<<<dim3(NTILES * NBR), dim3(768), 0, stream>>>(x, w1img, w2img, b1, b2, lnw, lnb, out);
}